// Round 1
// baseline (377.815 us; speedup 1.0000x reference)
//
#include <hip/hip_runtime.h>

#define NNODE 50000
#define NEDGE 800000
#define NTOT  (NEDGE + NNODE)   // 850000 edges incl. self loops
#define NB_SCAN 49              // ceil(50000/1024)

// ---------------- GEMM: h1[N,256] = x[N,128] @ W1[128,256] ----------------
__global__ __launch_bounds__(256) void k_gemm1(const float* __restrict__ x,
                                               const float* __restrict__ W1,
                                               float* __restrict__ h1) {
  __shared__ float xs[64 * 68];    // [row][k] stride 68 (2-way bank alias = free)
  __shared__ float wsh[64 * 64];   // [k][col] stride 64 (2-way = free)
  const int t = threadIdx.x;
  const int brow = (int)(blockIdx.x >> 2) * 64;
  const int bcol = (int)(blockIdx.x & 3) * 64;
  const int tx = t & 15, ty = t >> 4;
  float acc[4][4];
#pragma unroll
  for (int r = 0; r < 4; ++r)
#pragma unroll
    for (int c = 0; c < 4; ++c) acc[r][c] = 0.f;

  for (int kc = 0; kc < 2; ++kc) {
    if (kc) __syncthreads();
#pragma unroll
    for (int i = 0; i < 4; ++i) {
      int fi = t + i * 256;
      int r = fi >> 4, c4 = (fi & 15) << 2;
      int gr = brow + r;
      float4 v = make_float4(0.f, 0.f, 0.f, 0.f);
      if (gr < NNODE) v = *(const float4*)(x + gr * 128 + kc * 64 + c4);
      *(float4*)(xs + r * 68 + c4) = v;
    }
#pragma unroll
    for (int i = 0; i < 4; ++i) {
      int fi = t + i * 256;
      int r = fi >> 4, c4 = (fi & 15) << 2;
      float4 v = *(const float4*)(W1 + (kc * 64 + r) * 256 + bcol + c4);
      *(float4*)(wsh + r * 64 + c4) = v;
    }
    __syncthreads();
#pragma unroll 8
    for (int k = 0; k < 64; ++k) {
      float a[4], b[4];
#pragma unroll
      for (int r = 0; r < 4; ++r) a[r] = xs[(ty * 4 + r) * 68 + k];
#pragma unroll
      for (int c = 0; c < 4; ++c) b[c] = wsh[k * 64 + tx * 4 + c];
#pragma unroll
      for (int r = 0; r < 4; ++r)
#pragma unroll
        for (int c = 0; c < 4; ++c) acc[r][c] += a[r] * b[c];
    }
  }
#pragma unroll
  for (int r = 0; r < 4; ++r) {
    int gr = brow + ty * 4 + r;
    if (gr < NNODE) {
      float4 v = make_float4(acc[r][0], acc[r][1], acc[r][2], acc[r][3]);
      *(float4*)(h1 + gr * 256 + bcol + tx * 4) = v;
    }
  }
}

// -------- per-node attention logits: al_s1/al_d1[N,4] from h1 --------
__global__ __launch_bounds__(256) void k_al(const float* __restrict__ h1,
                                            const float* __restrict__ a_s1,
                                            const float* __restrict__ a_d1,
                                            float* __restrict__ als1,
                                            float* __restrict__ ald1) {
  const int w = threadIdx.x >> 6, lane = threadIdx.x & 63;
  const int n = (int)blockIdx.x * 4 + w;           // grid = 12500 -> n < 50000
  float4 v  = *(const float4*)(h1 + n * 256 + lane * 4);
  float4 as = *(const float4*)(a_s1 + lane * 4);
  float4 ad = *(const float4*)(a_d1 + lane * 4);
  float ps = v.x * as.x + v.y * as.y + v.z * as.z + v.w * as.w;
  float pd = v.x * ad.x + v.y * ad.y + v.z * ad.z + v.w * ad.w;
#pragma unroll
  for (int m = 1; m < 16; m <<= 1) {
    ps += __shfl_xor(ps, m, 64);
    pd += __shfl_xor(pd, m, 64);
  }
  if ((lane & 15) == 0) {
    int h = lane >> 4;
    als1[n * 4 + h] = ps;
    ald1[n * 4 + h] = pd;
  }
}

// ---------------- CSR build ----------------
__global__ void k_deg(const int* __restrict__ ei, int* __restrict__ deg) {
  int i = (int)blockIdx.x * blockDim.x + threadIdx.x;
  if (i >= NTOT) return;
  int d = (i < NEDGE) ? ei[NEDGE + i] : (i - NEDGE);
  atomicAdd(deg + d, 1);
}

__global__ __launch_bounds__(1024) void k_scan1(const int* __restrict__ deg,
                                                int* __restrict__ rowptr,
                                                int* __restrict__ bsum) {
  __shared__ int sh[1024];
  const int t = threadIdx.x;
  const int idx = (int)blockIdx.x * 1024 + t;
  int v = (idx < NNODE) ? deg[idx] : 0;
  sh[t] = v;
  __syncthreads();
#pragma unroll
  for (int off = 1; off < 1024; off <<= 1) {
    int add = (t >= off) ? sh[t - off] : 0;
    __syncthreads();
    sh[t] += add;
    __syncthreads();
  }
  if (idx < NNODE) rowptr[idx + 1] = sh[t];
  if (t == 1023) bsum[blockIdx.x] = sh[1023];
}

__global__ void k_scan2(const int* __restrict__ bsum, int* __restrict__ boff) {
  if (threadIdx.x == 0 && blockIdx.x == 0) {
    int acc = 0;
    for (int b = 0; b < NB_SCAN; ++b) { boff[b] = acc; acc += bsum[b]; }
  }
}

__global__ void k_scan3(const int* __restrict__ deg, int* __restrict__ rowptr,
                        const int* __restrict__ boff, int* __restrict__ cursor) {
  int idx = (int)blockIdx.x * blockDim.x + threadIdx.x;
  if (idx >= NNODE) return;
  int incl = rowptr[idx + 1] + boff[idx >> 10];
  rowptr[idx + 1] = incl;
  cursor[idx] = incl - deg[idx];
  if (idx == 0) rowptr[0] = 0;
}

__global__ void k_scatter(const int* __restrict__ ei, int* __restrict__ cursor,
                          int* __restrict__ esrc) {
  int i = (int)blockIdx.x * blockDim.x + threadIdx.x;
  if (i >= NTOT) return;
  int s, d;
  if (i < NEDGE) { s = ei[i]; d = ei[NEDGE + i]; }
  else           { s = i - NEDGE; d = s; }
  int pos = atomicAdd(cursor + d, 1);
  esrc[pos] = s;
}

// ------- layer-1 aggregate + bias + relu + layer-2 linear/logits -------
// one wave per dst node; lane owns 4 channels (head = lane>>4)
__global__ __launch_bounds__(256) void k_agg1(
    const float* __restrict__ h1, const float* __restrict__ als1,
    const float* __restrict__ ald1, const int* __restrict__ rowptr,
    const int* __restrict__ esrc, const float* __restrict__ b1,
    const float* __restrict__ W2, const float* __restrict__ a_s2,
    const float* __restrict__ a_d2, float* __restrict__ h2,
    float* __restrict__ al2s, float* __restrict__ al2d) {
  const int w = threadIdx.x >> 6, lane = threadIdx.x & 63;
  const int d = (int)blockIdx.x * 4 + w;           // grid = 12500
  const int head = lane >> 4;
  const float ald = ald1[d * 4 + head];
  const int begin = rowptr[d], end = rowptr[d + 1];
  float4 acc = make_float4(0.f, 0.f, 0.f, 0.f);
  float S = 0.f;
  for (int j = begin; j < end; ++j) {
    int s = esrc[j];
    float e = als1[s * 4 + head] + ald;
    e = e > 0.f ? e : 0.2f * e;
    float wgt = __expf(e);
    S += wgt;
    float4 hv = *(const float4*)(h1 + s * 256 + lane * 4);
    acc.x += wgt * hv.x;
    acc.y += wgt * hv.y;
    acc.z += wgt * hv.z;
    acc.w += wgt * hv.w;
  }
  const float inv = 1.f / S;
  float4 bb = *(const float4*)(b1 + lane * 4);
  float v0 = acc.x * inv + bb.x; v0 = v0 > 0.f ? v0 : 0.f;
  float v1 = acc.y * inv + bb.y; v1 = v1 > 0.f ? v1 : 0.f;
  float v2 = acc.z * inv + bb.z; v2 = v2 > 0.f ? v2 : 0.f;
  float v3 = acc.w * inv + bb.w; v3 = v3 > 0.f ? v3 : 0.f;
  // layer-2 linear: h2 = v @ W2 (256 -> 2)
  const int c = lane * 4;
  float p0 = v0 * W2[(c + 0) * 2 + 0] + v1 * W2[(c + 1) * 2 + 0] +
             v2 * W2[(c + 2) * 2 + 0] + v3 * W2[(c + 3) * 2 + 0];
  float p1 = v0 * W2[(c + 0) * 2 + 1] + v1 * W2[(c + 1) * 2 + 1] +
             v2 * W2[(c + 2) * 2 + 1] + v3 * W2[(c + 3) * 2 + 1];
#pragma unroll
  for (int m = 1; m < 64; m <<= 1) {
    p0 += __shfl_xor(p0, m, 64);
    p1 += __shfl_xor(p1, m, 64);
  }
  if (lane == 0) {
    h2[d * 2 + 0] = p0;
    h2[d * 2 + 1] = p1;
    al2s[d] = p0 * a_s2[0] + p1 * a_s2[1];
    al2d[d] = p0 * a_d2[0] + p1 * a_d2[1];
  }
}

// ---------------- layer-2 aggregate -> out ----------------
__global__ __launch_bounds__(256) void k_agg2(
    const float* __restrict__ h2, const float* __restrict__ al2s,
    const float* __restrict__ al2d, const int* __restrict__ rowptr,
    const int* __restrict__ esrc, const float* __restrict__ b2,
    float* __restrict__ out) {
  const int w = threadIdx.x >> 6, lane = threadIdx.x & 63;
  const int d = (int)blockIdx.x * 4 + w;           // grid = 12500
  const float ald = al2d[d];
  const int begin = rowptr[d], end = rowptr[d + 1];
  float S = 0.f, a0 = 0.f, a1 = 0.f;
  for (int j = begin + lane; j < end; j += 64) {
    int s = esrc[j];
    float e = al2s[s] + ald;
    e = e > 0.f ? e : 0.2f * e;
    float wgt = __expf(e);
    S += wgt;
    float2 hv = *(const float2*)(h2 + s * 2);
    a0 += wgt * hv.x;
    a1 += wgt * hv.y;
  }
#pragma unroll
  for (int m = 1; m < 64; m <<= 1) {
    S  += __shfl_xor(S, m, 64);
    a0 += __shfl_xor(a0, m, 64);
    a1 += __shfl_xor(a1, m, 64);
  }
  if (lane == 0) {
    float inv = 1.f / S;
    out[d * 2 + 0] = a0 * inv + b2[0];
    out[d * 2 + 1] = a1 * inv + b2[1];
  }
}

static inline size_t algn(size_t x) { return (x + 255) & ~(size_t)255; }

extern "C" void kernel_launch(void* const* d_in, const int* in_sizes, int n_in,
                              void* d_out, int out_size, void* d_ws, size_t ws_size,
                              hipStream_t stream) {
  const float* x    = (const float*)d_in[0];
  const int*   ei   = (const int*)d_in[1];
  const float* W1   = (const float*)d_in[2];
  const float* a_s1 = (const float*)d_in[3];
  const float* a_d1 = (const float*)d_in[4];
  const float* b1   = (const float*)d_in[5];
  const float* W2   = (const float*)d_in[6];
  const float* a_s2 = (const float*)d_in[7];
  const float* a_d2 = (const float*)d_in[8];
  const float* b2   = (const float*)d_in[9];
  float* out = (float*)d_out;

  char* w = (char*)d_ws;
  size_t o = 0;
  float* h1   = (float*)(w + o); o += algn((size_t)NNODE * 256 * 4);
  float* als1 = (float*)(w + o); o += algn((size_t)NNODE * 4 * 4);
  float* ald1 = (float*)(w + o); o += algn((size_t)NNODE * 4 * 4);
  int*   deg  = (int*)(w + o);   o += algn((size_t)NNODE * 4);
  int*   rowp = (int*)(w + o);   o += algn((size_t)(NNODE + 1) * 4);
  int*   curs = (int*)(w + o);   o += algn((size_t)NNODE * 4);
  int*   esrc = (int*)(w + o);   o += algn((size_t)NTOT * 4);
  int*   bsum = (int*)(w + o);   o += 256;
  int*   boff = (int*)(w + o);   o += 256;
  float* h2   = (float*)(w + o); o += algn((size_t)NNODE * 2 * 4);
  float* al2s = (float*)(w + o); o += algn((size_t)NNODE * 4);
  float* al2d = (float*)(w + o); o += algn((size_t)NNODE * 4);
  (void)ws_size; (void)n_in; (void)in_sizes; (void)out_size;

  hipMemsetAsync(deg, 0, (size_t)NNODE * 4, stream);

  k_gemm1<<<dim3(782 * 4), dim3(256), 0, stream>>>(x, W1, h1);
  k_al<<<dim3(12500), dim3(256), 0, stream>>>(h1, a_s1, a_d1, als1, ald1);
  k_deg<<<dim3((NTOT + 255) / 256), dim3(256), 0, stream>>>(ei, deg);
  k_scan1<<<dim3(NB_SCAN), dim3(1024), 0, stream>>>(deg, rowp, bsum);
  k_scan2<<<dim3(1), dim3(64), 0, stream>>>(bsum, boff);
  k_scan3<<<dim3((NNODE + 255) / 256), dim3(256), 0, stream>>>(deg, rowp, boff, curs);
  k_scatter<<<dim3((NTOT + 255) / 256), dim3(256), 0, stream>>>(ei, curs, esrc);
  k_agg1<<<dim3(12500), dim3(256), 0, stream>>>(h1, als1, ald1, rowp, esrc, b1,
                                                W2, a_s2, a_d2, h2, al2s, al2d);
  k_agg2<<<dim3(12500), dim3(256), 0, stream>>>(h2, al2s, al2d, rowp, esrc, b2, out);
}

// Round 2
// 316.329 us; speedup vs baseline: 1.1944x; 1.1944x over previous
//
#include <hip/hip_runtime.h>

#define NNODE 50000
#define NEDGE 800000
#define NTOT  (NEDGE + NNODE)   // 850000 edges incl. self loops
#define NB_SCAN 49              // ceil(50000/1024)

// ---- bf16 helpers (storage-only; all math in fp32) ----
__device__ __forceinline__ unsigned short f2bf(float f) {
  union { float f; unsigned u; } v; v.f = f;
  unsigned r = v.u + 0x7FFFu + ((v.u >> 16) & 1u);   // RN-even
  return (unsigned short)(r >> 16);
}
__device__ __forceinline__ float bflo(unsigned u) {
  union { unsigned u; float f; } v; v.u = u << 16; return v.f;
}
__device__ __forceinline__ float bfhi(unsigned u) {
  union { unsigned u; float f; } v; v.u = u & 0xFFFF0000u; return v.f;
}
__device__ __forceinline__ unsigned packbf(float a, float b) {
  return (unsigned)f2bf(a) | ((unsigned)f2bf(b) << 16);
}

// ---------------- GEMM: h1[N,256] = x[N,128] @ W1[128,256], bf16 out -------
__global__ __launch_bounds__(256) void k_gemm1(const float* __restrict__ x,
                                               const float* __restrict__ W1,
                                               unsigned short* __restrict__ h1b) {
  __shared__ float xs[64 * 68];    // [row][k] stride 68
  __shared__ float wsh[64 * 64];   // [k][col] stride 64
  const int t = threadIdx.x;
  const int brow = (int)(blockIdx.x >> 2) * 64;
  const int bcol = (int)(blockIdx.x & 3) * 64;
  const int tx = t & 15, ty = t >> 4;
  float acc[4][4];
#pragma unroll
  for (int r = 0; r < 4; ++r)
#pragma unroll
    for (int c = 0; c < 4; ++c) acc[r][c] = 0.f;

  for (int kc = 0; kc < 2; ++kc) {
    if (kc) __syncthreads();
#pragma unroll
    for (int i = 0; i < 4; ++i) {
      int fi = t + i * 256;
      int r = fi >> 4, c4 = (fi & 15) << 2;
      int gr = brow + r;
      float4 v = make_float4(0.f, 0.f, 0.f, 0.f);
      if (gr < NNODE) v = *(const float4*)(x + gr * 128 + kc * 64 + c4);
      *(float4*)(xs + r * 68 + c4) = v;
    }
#pragma unroll
    for (int i = 0; i < 4; ++i) {
      int fi = t + i * 256;
      int r = fi >> 4, c4 = (fi & 15) << 2;
      float4 v = *(const float4*)(W1 + (kc * 64 + r) * 256 + bcol + c4);
      *(float4*)(wsh + r * 64 + c4) = v;
    }
    __syncthreads();
#pragma unroll 8
    for (int k = 0; k < 64; ++k) {
      float a[4], b[4];
#pragma unroll
      for (int r = 0; r < 4; ++r) a[r] = xs[(ty * 4 + r) * 68 + k];
#pragma unroll
      for (int c = 0; c < 4; ++c) b[c] = wsh[k * 64 + tx * 4 + c];
#pragma unroll
      for (int r = 0; r < 4; ++r)
#pragma unroll
        for (int c = 0; c < 4; ++c) acc[r][c] += a[r] * b[c];
    }
  }
#pragma unroll
  for (int r = 0; r < 4; ++r) {
    int gr = brow + ty * 4 + r;
    if (gr < NNODE) {
      uint2 v = make_uint2(packbf(acc[r][0], acc[r][1]),
                           packbf(acc[r][2], acc[r][3]));
      *(uint2*)(h1b + gr * 256 + bcol + tx * 4) = v;
    }
  }
}

// -------- per-node attention logits: al_s1/al_d1[N,4] from h1 (bf16) -------
__global__ __launch_bounds__(256) void k_al(const unsigned short* __restrict__ h1b,
                                            const float* __restrict__ a_s1,
                                            const float* __restrict__ a_d1,
                                            float* __restrict__ als1,
                                            float* __restrict__ ald1) {
  const int w = threadIdx.x >> 6, lane = threadIdx.x & 63;
  const int n = (int)blockIdx.x * 4 + w;           // grid = 12500
  uint2 hv = *(const uint2*)(h1b + n * 256 + lane * 4);
  float v0 = bflo(hv.x), v1 = bfhi(hv.x), v2 = bflo(hv.y), v3 = bfhi(hv.y);
  float4 as = *(const float4*)(a_s1 + lane * 4);
  float4 ad = *(const float4*)(a_d1 + lane * 4);
  float ps = v0 * as.x + v1 * as.y + v2 * as.z + v3 * as.w;
  float pd = v0 * ad.x + v1 * ad.y + v2 * ad.z + v3 * ad.w;
#pragma unroll
  for (int m = 1; m < 16; m <<= 1) {
    ps += __shfl_xor(ps, m, 64);
    pd += __shfl_xor(pd, m, 64);
  }
  if ((lane & 15) == 0) {
    int h = lane >> 4;
    als1[n * 4 + h] = ps;
    ald1[n * 4 + h] = pd;
  }
}

// ---------------- CSR build ----------------
__global__ void k_deg(const int* __restrict__ ei, int* __restrict__ deg) {
  int i = (int)blockIdx.x * blockDim.x + threadIdx.x;
  if (i >= NTOT) return;
  int d = (i < NEDGE) ? ei[NEDGE + i] : (i - NEDGE);
  atomicAdd(deg + d, 1);
}

__global__ __launch_bounds__(1024) void k_scan1(const int* __restrict__ deg,
                                                int* __restrict__ rowptr,
                                                int* __restrict__ bsum) {
  __shared__ int sh[1024];
  const int t = threadIdx.x;
  const int idx = (int)blockIdx.x * 1024 + t;
  int v = (idx < NNODE) ? deg[idx] : 0;
  sh[t] = v;
  __syncthreads();
#pragma unroll
  for (int off = 1; off < 1024; off <<= 1) {
    int add = (t >= off) ? sh[t - off] : 0;
    __syncthreads();
    sh[t] += add;
    __syncthreads();
  }
  if (idx < NNODE) rowptr[idx + 1] = sh[t];
  if (t == 1023) bsum[blockIdx.x] = sh[1023];
}

__global__ void k_scan2(const int* __restrict__ bsum, int* __restrict__ boff) {
  if (threadIdx.x == 0 && blockIdx.x == 0) {
    int acc = 0;
    for (int b = 0; b < NB_SCAN; ++b) { boff[b] = acc; acc += bsum[b]; }
  }
}

__global__ void k_scan3(const int* __restrict__ deg, int* __restrict__ rowptr,
                        const int* __restrict__ boff, int* __restrict__ cursor) {
  int idx = (int)blockIdx.x * blockDim.x + threadIdx.x;
  if (idx >= NNODE) return;
  int incl = rowptr[idx + 1] + boff[idx >> 10];
  rowptr[idx + 1] = incl;
  cursor[idx] = incl - deg[idx];
  if (idx == 0) rowptr[0] = 0;
}

__global__ void k_scatter(const int* __restrict__ ei, int* __restrict__ cursor,
                          int* __restrict__ esrc) {
  int i = (int)blockIdx.x * blockDim.x + threadIdx.x;
  if (i >= NTOT) return;
  int s, d;
  if (i < NEDGE) { s = ei[i]; d = ei[NEDGE + i]; }
  else           { s = i - NEDGE; d = s; }
  int pos = atomicAdd(cursor + d, 1);
  esrc[pos] = s;
}

// ------- layer-1 aggregate + bias + relu + layer-2 linear/logits -------
// one wave per dst node; HALF-wave per edge (2 edges in flight), lane owns
// 8 channels (16B bf16 load). head = (lane&31)>>3.
__global__ __launch_bounds__(256) void k_agg1(
    const unsigned short* __restrict__ h1b, const float* __restrict__ als1,
    const float* __restrict__ ald1, const int* __restrict__ rowptr,
    const int* __restrict__ esrc, const float* __restrict__ b1,
    const float* __restrict__ W2, const float* __restrict__ a_s2,
    const float* __restrict__ a_d2, float* __restrict__ h2,
    float* __restrict__ al2s, float* __restrict__ al2d) {
  const int w = threadIdx.x >> 6, lane = threadIdx.x & 63;
  const int d = (int)blockIdx.x * 4 + w;           // grid = 12500
  const int half = lane >> 5, cl = lane & 31;
  const int head = cl >> 3;
  const float ald = ald1[d * 4 + head];
  const int begin = rowptr[d], end = rowptr[d + 1];
  float acc[8];
#pragma unroll
  for (int i = 0; i < 8; ++i) acc[i] = 0.f;
  float S = 0.f;

  int j = begin + half;
  int s = (j < end) ? esrc[j] : -1;
  while (s >= 0) {
    const uint4 hv = *(const uint4*)(h1b + (size_t)s * 256 + cl * 8);
    float e = als1[s * 4 + head] + ald;
    int jn = j + 2;
    int sn = (jn < end) ? esrc[jn] : -1;
    e = e > 0.f ? e : 0.2f * e;
    float wgt = __expf(e);
    S += wgt;
    acc[0] += wgt * bflo(hv.x); acc[1] += wgt * bfhi(hv.x);
    acc[2] += wgt * bflo(hv.y); acc[3] += wgt * bfhi(hv.y);
    acc[4] += wgt * bflo(hv.z); acc[5] += wgt * bfhi(hv.z);
    acc[6] += wgt * bflo(hv.w); acc[7] += wgt * bfhi(hv.w);
    j = jn; s = sn;
  }
  // combine the two half-waves (same channels, disjoint edges)
  S += __shfl_xor(S, 32, 64);
#pragma unroll
  for (int i = 0; i < 8; ++i) acc[i] += __shfl_xor(acc[i], 32, 64);

  const float inv = 1.f / S;
  const int c0 = cl * 8;
  float4 ba = *(const float4*)(b1 + c0);
  float4 bb = *(const float4*)(b1 + c0 + 4);
  float bias[8] = {ba.x, ba.y, ba.z, ba.w, bb.x, bb.y, bb.z, bb.w};
  // W2 rows for this lane's 8 channels: 16 contiguous floats
  float4 w0 = *(const float4*)(W2 + c0 * 2);
  float4 w1 = *(const float4*)(W2 + c0 * 2 + 4);
  float4 w2 = *(const float4*)(W2 + c0 * 2 + 8);
  float4 w3 = *(const float4*)(W2 + c0 * 2 + 12);
  float wa[16] = {w0.x, w0.y, w0.z, w0.w, w1.x, w1.y, w1.z, w1.w,
                  w2.x, w2.y, w2.z, w2.w, w3.x, w3.y, w3.z, w3.w};
  float p0 = 0.f, p1 = 0.f;
#pragma unroll
  for (int i = 0; i < 8; ++i) {
    float v = acc[i] * inv + bias[i];
    v = v > 0.f ? v : 0.f;
    p0 += v * wa[2 * i];
    p1 += v * wa[2 * i + 1];
  }
  // reduce over the 32-lane half (halves hold identical copies)
#pragma unroll
  for (int m = 1; m < 32; m <<= 1) {
    p0 += __shfl_xor(p0, m, 64);
    p1 += __shfl_xor(p1, m, 64);
  }
  if (lane == 0) {
    h2[d * 2 + 0] = p0;
    h2[d * 2 + 1] = p1;
    al2s[d] = p0 * a_s2[0] + p1 * a_s2[1];
    al2d[d] = p0 * a_d2[0] + p1 * a_d2[1];
  }
}

// ---------------- layer-2 aggregate -> out ----------------
__global__ __launch_bounds__(256) void k_agg2(
    const float* __restrict__ h2, const float* __restrict__ al2s,
    const float* __restrict__ al2d, const int* __restrict__ rowptr,
    const int* __restrict__ esrc, const float* __restrict__ b2,
    float* __restrict__ out) {
  const int w = threadIdx.x >> 6, lane = threadIdx.x & 63;
  const int d = (int)blockIdx.x * 4 + w;           // grid = 12500
  const float ald = al2d[d];
  const int begin = rowptr[d], end = rowptr[d + 1];
  float S = 0.f, a0 = 0.f, a1 = 0.f;
  for (int j = begin + lane; j < end; j += 64) {
    int s = esrc[j];
    float e = al2s[s] + ald;
    e = e > 0.f ? e : 0.2f * e;
    float wgt = __expf(e);
    S += wgt;
    float2 hv = *(const float2*)(h2 + s * 2);
    a0 += wgt * hv.x;
    a1 += wgt * hv.y;
  }
#pragma unroll
  for (int m = 1; m < 64; m <<= 1) {
    S  += __shfl_xor(S, m, 64);
    a0 += __shfl_xor(a0, m, 64);
    a1 += __shfl_xor(a1, m, 64);
  }
  if (lane == 0) {
    float inv = 1.f / S;
    out[d * 2 + 0] = a0 * inv + b2[0];
    out[d * 2 + 1] = a1 * inv + b2[1];
  }
}

static inline size_t algn(size_t x) { return (x + 255) & ~(size_t)255; }

extern "C" void kernel_launch(void* const* d_in, const int* in_sizes, int n_in,
                              void* d_out, int out_size, void* d_ws, size_t ws_size,
                              hipStream_t stream) {
  const float* x    = (const float*)d_in[0];
  const int*   ei   = (const int*)d_in[1];
  const float* W1   = (const float*)d_in[2];
  const float* a_s1 = (const float*)d_in[3];
  const float* a_d1 = (const float*)d_in[4];
  const float* b1   = (const float*)d_in[5];
  const float* W2   = (const float*)d_in[6];
  const float* a_s2 = (const float*)d_in[7];
  const float* a_d2 = (const float*)d_in[8];
  const float* b2   = (const float*)d_in[9];
  float* out = (float*)d_out;

  char* w = (char*)d_ws;
  size_t o = 0;
  unsigned short* h1b = (unsigned short*)(w + o); o += algn((size_t)NNODE * 256 * 2);
  float* als1 = (float*)(w + o); o += algn((size_t)NNODE * 4 * 4);
  float* ald1 = (float*)(w + o); o += algn((size_t)NNODE * 4 * 4);
  int*   deg  = (int*)(w + o);   o += algn((size_t)NNODE * 4);
  int*   rowp = (int*)(w + o);   o += algn((size_t)(NNODE + 1) * 4);
  int*   curs = (int*)(w + o);   o += algn((size_t)NNODE * 4);
  int*   esrc = (int*)(w + o);   o += algn((size_t)NTOT * 4);
  int*   bsum = (int*)(w + o);   o += 256;
  int*   boff = (int*)(w + o);   o += 256;
  float* h2   = (float*)(w + o); o += algn((size_t)NNODE * 2 * 4);
  float* al2s = (float*)(w + o); o += algn((size_t)NNODE * 4);
  float* al2d = (float*)(w + o); o += algn((size_t)NNODE * 4);
  (void)ws_size; (void)n_in; (void)in_sizes; (void)out_size;

  hipMemsetAsync(deg, 0, (size_t)NNODE * 4, stream);

  k_gemm1<<<dim3(782 * 4), dim3(256), 0, stream>>>(x, W1, h1b);
  k_al<<<dim3(12500), dim3(256), 0, stream>>>(h1b, a_s1, a_d1, als1, ald1);
  k_deg<<<dim3((NTOT + 255) / 256), dim3(256), 0, stream>>>(ei, deg);
  k_scan1<<<dim3(NB_SCAN), dim3(1024), 0, stream>>>(deg, rowp, bsum);
  k_scan2<<<dim3(1), dim3(64), 0, stream>>>(bsum, boff);
  k_scan3<<<dim3((NNODE + 255) / 256), dim3(256), 0, stream>>>(deg, rowp, boff, curs);
  k_scatter<<<dim3((NTOT + 255) / 256), dim3(256), 0, stream>>>(ei, curs, esrc);
  k_agg1<<<dim3(12500), dim3(256), 0, stream>>>(h1b, als1, ald1, rowp, esrc, b1,
                                                W2, a_s2, a_d2, h2, al2s, al2d);
  k_agg2<<<dim3(12500), dim3(256), 0, stream>>>(h2, al2s, al2d, rowp, esrc, b2, out);
}

// Round 3
// 293.457 us; speedup vs baseline: 1.2875x; 1.0779x over previous
//
#include <hip/hip_runtime.h>

#define NNODE 50000
#define NEDGE 800000
#define NTOT  (NEDGE + NNODE)   // 850000 edges incl. self loops
#define NB_SCAN 49              // ceil(50000/1024)

typedef __attribute__((ext_vector_type(8))) short bf16x8;
typedef __attribute__((ext_vector_type(4))) float f32x4;
union U4B8 { uint4 u; bf16x8 b; };

// ---- bf16 helpers (storage-only; all math in fp32) ----
__device__ __forceinline__ unsigned short f2bf(float f) {
  union { float f; unsigned u; } v; v.f = f;
  unsigned r = v.u + 0x7FFFu + ((v.u >> 16) & 1u);   // RN-even
  return (unsigned short)(r >> 16);
}
__device__ __forceinline__ float bflo(unsigned u) {
  union { unsigned u; float f; } v; v.u = u << 16; return v.f;
}
__device__ __forceinline__ float bfhi(unsigned u) {
  union { unsigned u; float f; } v; v.u = u & 0xFFFF0000u; return v.f;
}
__device__ __forceinline__ unsigned packbf(float a, float b) {
  return (unsigned)f2bf(a) | ((unsigned)f2bf(b) << 16);
}

// ---- W1 -> bf16 transposed [256 cols][128 k] for MFMA B-frag loads ----
__global__ __launch_bounds__(256) void k_w1t(const float* __restrict__ W1,
                                             unsigned short* __restrict__ W1bT) {
  int flat = (int)blockIdx.x * 256 + threadIdx.x;   // 8192 total
  int k = flat >> 6, c4 = (flat & 63) << 2;
  float4 v = *(const float4*)(W1 + k * 256 + c4);
  W1bT[(c4 + 0) * 128 + k] = f2bf(v.x);
  W1bT[(c4 + 1) * 128 + k] = f2bf(v.y);
  W1bT[(c4 + 2) * 128 + k] = f2bf(v.z);
  W1bT[(c4 + 3) * 128 + k] = f2bf(v.w);
}

// ---- MFMA GEMM: h1b[N,256](bf16) = bf16(x[N,128]) @ bf16(W1) ----
// block = 64 rows x 128 cols (2 heads); wave = 32 rows x 64 cols (1 head).
// Fused epilogue computes als1/ald1 from fp32 accumulators.
__global__ __launch_bounds__(256) void k_gemm1(
    const float* __restrict__ x, const unsigned short* __restrict__ W1bT,
    const float* __restrict__ a_s1, const float* __restrict__ a_d1,
    unsigned short* __restrict__ h1b, float* __restrict__ als1,
    float* __restrict__ ald1) {
  __shared__ unsigned short xs[64 * 136];   // A tile bf16, padded stride
  const int t = threadIdx.x;
  const int rb = (int)blockIdx.x >> 1, nhalf = (int)blockIdx.x & 1;
  const int grow0 = rb * 64;
  // stage A: 64x128 fp32 -> bf16 LDS
#pragma unroll
  for (int i = 0; i < 8; ++i) {
    int f = t + i * 256;
    int row = f >> 5, c4 = (f & 31) << 2;
    int gr = grow0 + row;
    float4 v = make_float4(0.f, 0.f, 0.f, 0.f);
    if (gr < NNODE) v = *(const float4*)(x + gr * 128 + c4);
    *(uint2*)(xs + row * 136 + c4) = make_uint2(packbf(v.x, v.y), packbf(v.z, v.w));
  }
  const int wid = t >> 6, lane = t & 63;
  const int wrow = (wid >> 1) * 32;           // wave's 32-row group
  const int head = nhalf * 2 + (wid & 1);     // wave's 64-col slab = one head
  const int c_lo = lane & 15, g = lane >> 4;
  // B-frags from global (64KB, L2-hot): B[k][col], lane holds 8 k for col c
  U4B8 bfr[4][4];
#pragma unroll
  for (int nr = 0; nr < 4; ++nr) {
    int c = head * 64 + nr * 16 + c_lo;
#pragma unroll
    for (int ks = 0; ks < 4; ++ks)
      bfr[nr][ks].u = *(const uint4*)(W1bT + c * 128 + ks * 32 + g * 8);
  }
  __syncthreads();
  // A-frags: lane holds 8 k for row (wrow + mr*16 + c_lo)
  U4B8 afr[2][4];
#pragma unroll
  for (int mr = 0; mr < 2; ++mr)
#pragma unroll
    for (int ks = 0; ks < 4; ++ks)
      afr[mr][ks].u = *(const uint4*)(xs + (wrow + mr * 16 + c_lo) * 136 + ks * 32 + g * 8);
  f32x4 acc[2][4];
#pragma unroll
  for (int mr = 0; mr < 2; ++mr)
#pragma unroll
    for (int nr = 0; nr < 4; ++nr) acc[mr][nr] = (f32x4){0.f, 0.f, 0.f, 0.f};
#pragma unroll
  for (int ks = 0; ks < 4; ++ks)
#pragma unroll
    for (int mr = 0; mr < 2; ++mr)
#pragma unroll
      for (int nr = 0; nr < 4; ++nr)
        acc[mr][nr] = __builtin_amdgcn_mfma_f32_16x16x32_bf16(
            afr[mr][ks].b, bfr[nr][ks].b, acc[mr][nr], 0, 0, 0);
  // ---- attention-logit epilogue (full head dot within this wave) ----
  float as_v[4], ad_v[4];
#pragma unroll
  for (int nr = 0; nr < 4; ++nr) {
    as_v[nr] = a_s1[head * 64 + nr * 16 + c_lo];
    ad_v[nr] = a_d1[head * 64 + nr * 16 + c_lo];
  }
  float ps[2][4], pd[2][4];
#pragma unroll
  for (int mr = 0; mr < 2; ++mr)
#pragma unroll
    for (int r = 0; r < 4; ++r) {
      float s = 0.f, dsum = 0.f;
#pragma unroll
      for (int nr = 0; nr < 4; ++nr) {
        s += acc[mr][nr][r] * as_v[nr];
        dsum += acc[mr][nr][r] * ad_v[nr];
      }
      ps[mr][r] = s; pd[mr][r] = dsum;
    }
#pragma unroll
  for (int m = 1; m < 16; m <<= 1)
#pragma unroll
    for (int mr = 0; mr < 2; ++mr)
#pragma unroll
      for (int r = 0; r < 4; ++r) {
        ps[mr][r] += __shfl_xor(ps[mr][r], m, 64);
        pd[mr][r] += __shfl_xor(pd[mr][r], m, 64);
      }
  if (c_lo == 0) {
#pragma unroll
    for (int mr = 0; mr < 2; ++mr)
#pragma unroll
      for (int r = 0; r < 4; ++r) {
        int node = grow0 + wrow + mr * 16 + g * 4 + r;
        if (node < NNODE) {
          als1[node * 4 + head] = ps[mr][r];
          ald1[node * 4 + head] = pd[mr][r];
        }
      }
  }
  // ---- store h1b via wave-private LDS transpose -> coalesced uint4 ----
  __syncthreads();
  unsigned short* tb = xs + wid * 2048;   // 32x64 bf16 = 4KB per wave
#pragma unroll
  for (int mr = 0; mr < 2; ++mr)
#pragma unroll
    for (int nr = 0; nr < 4; ++nr)
#pragma unroll
      for (int r = 0; r < 4; ++r)
        tb[(mr * 16 + g * 4 + r) * 64 + nr * 16 + c_lo] = f2bf(acc[mr][nr][r]);
#pragma unroll
  for (int i = 0; i < 4; ++i) {
    int unit = i * 64 + lane;
    int row = unit >> 3, cS = (unit & 7) * 8;
    int node = grow0 + wrow + row;
    if (node < NNODE) {
      uint4 v = *(const uint4*)(tb + unit * 8);
      *(uint4*)(h1b + (size_t)node * 256 + nhalf * 128 + (wid & 1) * 64 + cS) = v;
    }
  }
}

// ---------------- CSR build ----------------
__global__ void k_deg(const int* __restrict__ ei, int* __restrict__ deg) {
  int i = (int)blockIdx.x * blockDim.x + threadIdx.x;
  if (i >= NTOT) return;
  int d = (i < NEDGE) ? ei[NEDGE + i] : (i - NEDGE);
  atomicAdd(deg + d, 1);
}

__global__ __launch_bounds__(1024) void k_scan1(const int* __restrict__ deg,
                                                int* __restrict__ rowptr,
                                                int* __restrict__ bsum) {
  __shared__ int sh[1024];
  const int t = threadIdx.x;
  const int idx = (int)blockIdx.x * 1024 + t;
  int v = (idx < NNODE) ? deg[idx] : 0;
  sh[t] = v;
  __syncthreads();
#pragma unroll
  for (int off = 1; off < 1024; off <<= 1) {
    int add = (t >= off) ? sh[t - off] : 0;
    __syncthreads();
    sh[t] += add;
    __syncthreads();
  }
  if (idx < NNODE) rowptr[idx + 1] = sh[t];
  if (t == 1023) bsum[blockIdx.x] = sh[1023];
}

__global__ void k_scan2(const int* __restrict__ bsum, int* __restrict__ boff) {
  if (threadIdx.x == 0 && blockIdx.x == 0) {
    int acc = 0;
    for (int b = 0; b < NB_SCAN; ++b) { boff[b] = acc; acc += bsum[b]; }
  }
}

__global__ void k_scan3(const int* __restrict__ deg, int* __restrict__ rowptr,
                        const int* __restrict__ boff, int* __restrict__ cursor) {
  int idx = (int)blockIdx.x * blockDim.x + threadIdx.x;
  if (idx >= NNODE) return;
  int incl = rowptr[idx + 1] + boff[idx >> 10];
  rowptr[idx + 1] = incl;
  cursor[idx] = incl - deg[idx];
  if (idx == 0) rowptr[0] = 0;
}

__global__ void k_scatter(const int* __restrict__ ei, int* __restrict__ cursor,
                          int* __restrict__ esrc) {
  int i = (int)blockIdx.x * blockDim.x + threadIdx.x;
  if (i >= NTOT) return;
  int s, d;
  if (i < NEDGE) { s = ei[i]; d = ei[NEDGE + i]; }
  else           { s = i - NEDGE; d = s; }
  int pos = atomicAdd(cursor + d, 1);
  esrc[pos] = s;
}

// ------- layer-1 aggregate + bias + relu + layer-2 linear/logits -------
// one wave per dst node; half-wave per edge; 2-deep software pipeline.
__global__ __launch_bounds__(256) void k_agg1(
    const unsigned short* __restrict__ h1b, const float* __restrict__ als1,
    const float* __restrict__ ald1, const int* __restrict__ rowptr,
    const int* __restrict__ esrc, const float* __restrict__ b1,
    const float* __restrict__ W2, const float* __restrict__ a_s2,
    const float* __restrict__ a_d2, float* __restrict__ h2,
    float* __restrict__ al2s, float* __restrict__ al2d) {
  const int w = threadIdx.x >> 6, lane = threadIdx.x & 63;
  const int d = (int)blockIdx.x * 4 + w;           // grid = 12500
  const int half = lane >> 5, cl = lane & 31;
  const int head = cl >> 3;
  const float ald = ald1[d * 4 + head];
  const int begin = rowptr[d], end = rowptr[d + 1];
  float acc[8];
#pragma unroll
  for (int i = 0; i < 8; ++i) acc[i] = 0.f;
  float S = 0.f;

  int j = begin + half;
  int s = (j < end) ? esrc[j] : -1;
  uint4 hv = make_uint4(0, 0, 0, 0);
  float el = 0.f;
  if (s >= 0) {
    hv = *(const uint4*)(h1b + (size_t)s * 256 + cl * 8);
    el = als1[s * 4 + head];
  }
  while (s >= 0) {
    int jn = j + 2;
    int sn = (jn < end) ? esrc[jn] : -1;
    uint4 hvn = make_uint4(0, 0, 0, 0);
    float eln = 0.f;
    if (sn >= 0) {
      hvn = *(const uint4*)(h1b + (size_t)sn * 256 + cl * 8);
      eln = als1[sn * 4 + head];
    }
    float e = el + ald;
    e = fmaxf(e, 0.2f * e);               // leaky relu
    float wgt = __expf(e);
    S += wgt;
    acc[0] += wgt * bflo(hv.x); acc[1] += wgt * bfhi(hv.x);
    acc[2] += wgt * bflo(hv.y); acc[3] += wgt * bfhi(hv.y);
    acc[4] += wgt * bflo(hv.z); acc[5] += wgt * bfhi(hv.z);
    acc[6] += wgt * bflo(hv.w); acc[7] += wgt * bfhi(hv.w);
    j = jn; s = sn; hv = hvn; el = eln;
  }
  // combine the two half-waves (same channels, disjoint edges)
  S += __shfl_xor(S, 32, 64);
#pragma unroll
  for (int i = 0; i < 8; ++i) acc[i] += __shfl_xor(acc[i], 32, 64);

  const float inv = 1.f / S;
  const int c0 = cl * 8;
  float4 ba = *(const float4*)(b1 + c0);
  float4 bb = *(const float4*)(b1 + c0 + 4);
  float bias[8] = {ba.x, ba.y, ba.z, ba.w, bb.x, bb.y, bb.z, bb.w};
  float4 w0 = *(const float4*)(W2 + c0 * 2);
  float4 w1 = *(const float4*)(W2 + c0 * 2 + 4);
  float4 w2 = *(const float4*)(W2 + c0 * 2 + 8);
  float4 w3 = *(const float4*)(W2 + c0 * 2 + 12);
  float wa[16] = {w0.x, w0.y, w0.z, w0.w, w1.x, w1.y, w1.z, w1.w,
                  w2.x, w2.y, w2.z, w2.w, w3.x, w3.y, w3.z, w3.w};
  float p0 = 0.f, p1 = 0.f;
#pragma unroll
  for (int i = 0; i < 8; ++i) {
    float v = acc[i] * inv + bias[i];
    v = v > 0.f ? v : 0.f;
    p0 += v * wa[2 * i];
    p1 += v * wa[2 * i + 1];
  }
#pragma unroll
  for (int m = 1; m < 32; m <<= 1) {
    p0 += __shfl_xor(p0, m, 64);
    p1 += __shfl_xor(p1, m, 64);
  }
  if (lane == 0) {
    h2[d * 2 + 0] = p0;
    h2[d * 2 + 1] = p1;
    al2s[d] = p0 * a_s2[0] + p1 * a_s2[1];
    al2d[d] = p0 * a_d2[0] + p1 * a_d2[1];
  }
}

// ---------------- layer-2 aggregate -> out ----------------
__global__ __launch_bounds__(256) void k_agg2(
    const float* __restrict__ h2, const float* __restrict__ al2s,
    const float* __restrict__ al2d, const int* __restrict__ rowptr,
    const int* __restrict__ esrc, const float* __restrict__ b2,
    float* __restrict__ out) {
  const int w = threadIdx.x >> 6, lane = threadIdx.x & 63;
  const int d = (int)blockIdx.x * 4 + w;           // grid = 12500
  const float ald = al2d[d];
  const int begin = rowptr[d], end = rowptr[d + 1];
  float S = 0.f, a0 = 0.f, a1 = 0.f;
  for (int j = begin + lane; j < end; j += 64) {
    int s = esrc[j];
    float e = al2s[s] + ald;
    e = fmaxf(e, 0.2f * e);
    float wgt = __expf(e);
    S += wgt;
    float2 hv = *(const float2*)(h2 + s * 2);
    a0 += wgt * hv.x;
    a1 += wgt * hv.y;
  }
#pragma unroll
  for (int m = 1; m < 64; m <<= 1) {
    S  += __shfl_xor(S, m, 64);
    a0 += __shfl_xor(a0, m, 64);
    a1 += __shfl_xor(a1, m, 64);
  }
  if (lane == 0) {
    float inv = 1.f / S;
    out[d * 2 + 0] = a0 * inv + b2[0];
    out[d * 2 + 1] = a1 * inv + b2[1];
  }
}

static inline size_t algn(size_t x) { return (x + 255) & ~(size_t)255; }

extern "C" void kernel_launch(void* const* d_in, const int* in_sizes, int n_in,
                              void* d_out, int out_size, void* d_ws, size_t ws_size,
                              hipStream_t stream) {
  const float* x    = (const float*)d_in[0];
  const int*   ei   = (const int*)d_in[1];
  const float* W1   = (const float*)d_in[2];
  const float* a_s1 = (const float*)d_in[3];
  const float* a_d1 = (const float*)d_in[4];
  const float* b1   = (const float*)d_in[5];
  const float* W2   = (const float*)d_in[6];
  const float* a_s2 = (const float*)d_in[7];
  const float* a_d2 = (const float*)d_in[8];
  const float* b2   = (const float*)d_in[9];
  float* out = (float*)d_out;

  char* w = (char*)d_ws;
  size_t o = 0;
  unsigned short* h1b = (unsigned short*)(w + o); o += algn((size_t)NNODE * 256 * 2);
  unsigned short* W1bT = (unsigned short*)(w + o); o += algn((size_t)256 * 128 * 2);
  float* als1 = (float*)(w + o); o += algn((size_t)NNODE * 4 * 4);
  float* ald1 = (float*)(w + o); o += algn((size_t)NNODE * 4 * 4);
  int*   deg  = (int*)(w + o);   o += algn((size_t)NNODE * 4);
  int*   rowp = (int*)(w + o);   o += algn((size_t)(NNODE + 1) * 4);
  int*   curs = (int*)(w + o);   o += algn((size_t)NNODE * 4);
  int*   esrc = (int*)(w + o);   o += algn((size_t)NTOT * 4);
  int*   bsum = (int*)(w + o);   o += 256;
  int*   boff = (int*)(w + o);   o += 256;
  float* h2   = (float*)(w + o); o += algn((size_t)NNODE * 2 * 4);
  float* al2s = (float*)(w + o); o += algn((size_t)NNODE * 4);
  float* al2d = (float*)(w + o); o += algn((size_t)NNODE * 4);
  (void)ws_size; (void)n_in; (void)in_sizes; (void)out_size;

  hipMemsetAsync(deg, 0, (size_t)NNODE * 4, stream);

  k_w1t<<<dim3(32), dim3(256), 0, stream>>>(W1, W1bT);
  k_gemm1<<<dim3(782 * 2), dim3(256), 0, stream>>>(x, W1bT, a_s1, a_d1,
                                                   h1b, als1, ald1);
  k_deg<<<dim3((NTOT + 255) / 256), dim3(256), 0, stream>>>(ei, deg);
  k_scan1<<<dim3(NB_SCAN), dim3(1024), 0, stream>>>(deg, rowp, bsum);
  k_scan2<<<dim3(1), dim3(64), 0, stream>>>(bsum, boff);
  k_scan3<<<dim3((NNODE + 255) / 256), dim3(256), 0, stream>>>(deg, rowp, boff, curs);
  k_scatter<<<dim3((NTOT + 255) / 256), dim3(256), 0, stream>>>(ei, curs, esrc);
  k_agg1<<<dim3(12500), dim3(256), 0, stream>>>(h1b, als1, ald1, rowp, esrc, b1,
                                                W2, a_s2, a_d2, h2, al2s, al2d);
  k_agg2<<<dim3(12500), dim3(256), 0, stream>>>(h2, al2s, al2d, rowp, esrc, b2, out);
}

// Round 5
// 262.727 us; speedup vs baseline: 1.4381x; 1.1170x over previous
//
#include <hip/hip_runtime.h>

#define NNODE 50000
#define NEDGE 800000
#define NTOT  (NEDGE + NNODE)   // 850000 edges incl. self loops
#define NB_SCAN 49              // ceil(50000/1024)
#define NGEMM 1564              // 782 row-blocks x 2 col-halves

typedef __attribute__((ext_vector_type(8))) short bf16x8;
typedef __attribute__((ext_vector_type(4))) float f32x4;
union U4B8 { uint4 u; bf16x8 b; };

// ---- bf16 helpers (storage-only; all math in fp32) ----
__device__ __forceinline__ unsigned short f2bf(float f) {
  union { float f; unsigned u; } v; v.f = f;
  unsigned r = v.u + 0x7FFFu + ((v.u >> 16) & 1u);   // RN-even
  return (unsigned short)(r >> 16);
}
__device__ __forceinline__ float bflo(unsigned u) {
  union { unsigned u; float f; } v; v.u = u << 16; return v.f;
}
__device__ __forceinline__ float bfhi(unsigned u) {
  union { unsigned u; float f; } v; v.u = u & 0xFFFF0000u; return v.f;
}
__device__ __forceinline__ unsigned packbf(float a, float b) {
  return (unsigned)f2bf(a) | ((unsigned)f2bf(b) << 16);
}

// ---- prep: W1 -> bf16 transposed [256][128] + zero deg (one dispatch) ----
__global__ __launch_bounds__(256) void k_prep(const float* __restrict__ W1,
                                              unsigned short* __restrict__ W1bT,
                                              int* __restrict__ deg) {
  const int b = (int)blockIdx.x;
  if (b < 32) {
    int flat = b * 256 + threadIdx.x;   // 8192 total
    int k = flat >> 6, c4 = (flat & 63) << 2;
    float4 v = *(const float4*)(W1 + k * 256 + c4);
    W1bT[(c4 + 0) * 128 + k] = f2bf(v.x);
    W1bT[(c4 + 1) * 128 + k] = f2bf(v.y);
    W1bT[(c4 + 2) * 128 + k] = f2bf(v.z);
    W1bT[(c4 + 3) * 128 + k] = f2bf(v.w);
  } else {
    int i = (b - 32) * 256 + threadIdx.x;
    if (i < NNODE) deg[i] = 0;
  }
}

// ---- fused: MFMA GEMM (blocks < NGEMM) + degree histogram (rest) ----
// gemm: block = 64 rows x 128 cols (2 heads); wave = 32 rows x 64 cols.
// Fused epilogue computes als1/ald1 from fp32 accumulators.
__global__ __launch_bounds__(256) void k_gemm_deg(
    const float* __restrict__ x, const unsigned short* __restrict__ W1bT,
    const float* __restrict__ a_s1, const float* __restrict__ a_d1,
    unsigned short* __restrict__ h1b, float* __restrict__ als1,
    float* __restrict__ ald1, const int* __restrict__ ei,
    int* __restrict__ deg) {
  __shared__ unsigned short xs[64 * 136];
  if ((int)blockIdx.x >= NGEMM) {
    int i = ((int)blockIdx.x - NGEMM) * 256 + threadIdx.x;
    if (i < NTOT) {
      int d = (i < NEDGE) ? ei[NEDGE + i] : (i - NEDGE);
      atomicAdd(deg + d, 1);
    }
    return;
  }
  const int t = threadIdx.x;
  const int rb = (int)blockIdx.x >> 1, nhalf = (int)blockIdx.x & 1;
  const int grow0 = rb * 64;
  // stage A: 64x128 fp32 -> bf16 LDS
#pragma unroll
  for (int i = 0; i < 8; ++i) {
    int f = t + i * 256;
    int row = f >> 5, c4 = (f & 31) << 2;
    int gr = grow0 + row;
    float4 v = make_float4(0.f, 0.f, 0.f, 0.f);
    if (gr < NNODE) v = *(const float4*)(x + gr * 128 + c4);
    *(uint2*)(xs + row * 136 + c4) = make_uint2(packbf(v.x, v.y), packbf(v.z, v.w));
  }
  const int wid = t >> 6, lane = t & 63;
  const int wrow = (wid >> 1) * 32;
  const int head = nhalf * 2 + (wid & 1);
  const int c_lo = lane & 15, g = lane >> 4;
  U4B8 bfr[4][4];
#pragma unroll
  for (int nr = 0; nr < 4; ++nr) {
    int c = head * 64 + nr * 16 + c_lo;
#pragma unroll
    for (int ks = 0; ks < 4; ++ks)
      bfr[nr][ks].u = *(const uint4*)(W1bT + c * 128 + ks * 32 + g * 8);
  }
  __syncthreads();
  U4B8 afr[2][4];
#pragma unroll
  for (int mr = 0; mr < 2; ++mr)
#pragma unroll
    for (int ks = 0; ks < 4; ++ks)
      afr[mr][ks].u = *(const uint4*)(xs + (wrow + mr * 16 + c_lo) * 136 + ks * 32 + g * 8);
  f32x4 acc[2][4];
#pragma unroll
  for (int mr = 0; mr < 2; ++mr)
#pragma unroll
    for (int nr = 0; nr < 4; ++nr) acc[mr][nr] = (f32x4){0.f, 0.f, 0.f, 0.f};
#pragma unroll
  for (int ks = 0; ks < 4; ++ks)
#pragma unroll
    for (int mr = 0; mr < 2; ++mr)
#pragma unroll
      for (int nr = 0; nr < 4; ++nr)
        acc[mr][nr] = __builtin_amdgcn_mfma_f32_16x16x32_bf16(
            afr[mr][ks].b, bfr[nr][ks].b, acc[mr][nr], 0, 0, 0);
  // ---- attention-logit epilogue ----
  float as_v[4], ad_v[4];
#pragma unroll
  for (int nr = 0; nr < 4; ++nr) {
    as_v[nr] = a_s1[head * 64 + nr * 16 + c_lo];
    ad_v[nr] = a_d1[head * 64 + nr * 16 + c_lo];
  }
  float ps[2][4], pd[2][4];
#pragma unroll
  for (int mr = 0; mr < 2; ++mr)
#pragma unroll
    for (int r = 0; r < 4; ++r) {
      float s = 0.f, dsum = 0.f;
#pragma unroll
      for (int nr = 0; nr < 4; ++nr) {
        s += acc[mr][nr][r] * as_v[nr];
        dsum += acc[mr][nr][r] * ad_v[nr];
      }
      ps[mr][r] = s; pd[mr][r] = dsum;
    }
#pragma unroll
  for (int m = 1; m < 16; m <<= 1)
#pragma unroll
    for (int mr = 0; mr < 2; ++mr)
#pragma unroll
      for (int r = 0; r < 4; ++r) {
        ps[mr][r] += __shfl_xor(ps[mr][r], m, 64);
        pd[mr][r] += __shfl_xor(pd[mr][r], m, 64);
      }
  if (c_lo == 0) {
#pragma unroll
    for (int mr = 0; mr < 2; ++mr)
#pragma unroll
      for (int r = 0; r < 4; ++r) {
        int node = grow0 + wrow + mr * 16 + g * 4 + r;
        if (node < NNODE) {
          als1[node * 4 + head] = ps[mr][r];
          ald1[node * 4 + head] = pd[mr][r];
        }
      }
  }
  // ---- store h1b via wave-private LDS transpose ----
  __syncthreads();
  unsigned short* tb = xs + wid * 2048;
#pragma unroll
  for (int mr = 0; mr < 2; ++mr)
#pragma unroll
    for (int nr = 0; nr < 4; ++nr)
#pragma unroll
      for (int r = 0; r < 4; ++r)
        tb[(mr * 16 + g * 4 + r) * 64 + nr * 16 + c_lo] = f2bf(acc[mr][nr][r]);
#pragma unroll
  for (int i = 0; i < 4; ++i) {
    int unit = i * 64 + lane;
    int row = unit >> 3, cS = (unit & 7) * 8;
    int node = grow0 + wrow + row;
    if (node < NNODE) {
      uint4 v = *(const uint4*)(tb + unit * 8);
      *(uint4*)(h1b + (size_t)node * 256 + nhalf * 128 + (wid & 1) * 64 + cS) = v;
    }
  }
}

// ---------------- CSR scan ----------------
__global__ __launch_bounds__(1024) void k_scan1(const int* __restrict__ deg,
                                                int* __restrict__ rowptr,
                                                int* __restrict__ bsum) {
  __shared__ int sh[1024];
  const int t = threadIdx.x;
  const int idx = (int)blockIdx.x * 1024 + t;
  int v = (idx < NNODE) ? deg[idx] : 0;
  sh[t] = v;
  __syncthreads();
#pragma unroll
  for (int off = 1; off < 1024; off <<= 1) {
    int add = (t >= off) ? sh[t - off] : 0;
    __syncthreads();
    sh[t] += add;
    __syncthreads();
  }
  if (idx < NNODE) rowptr[idx + 1] = sh[t];
  if (t == 1023) bsum[blockIdx.x] = sh[1023];
}

// block-local wave scan of the 49 block sums; finalize rowptr + cursor
__global__ __launch_bounds__(256) void k_scan23(const int* __restrict__ deg,
                                                int* __restrict__ rowptr,
                                                const int* __restrict__ bsum,
                                                int* __restrict__ cursor) {
  __shared__ int boff[64];
  const int t = threadIdx.x;
  if (t < 64) {
    int v = (t < NB_SCAN) ? bsum[t] : 0;
    int orig = v;
#pragma unroll
    for (int off = 1; off < 64; off <<= 1) {
      int n = __shfl_up(v, off, 64);
      if (t >= off) v += n;
    }
    boff[t] = v - orig;   // exclusive prefix
  }
  __syncthreads();
  int idx = (int)blockIdx.x * 256 + t;
  if (idx < NNODE) {
    int incl = rowptr[idx + 1] + boff[idx >> 10];
    rowptr[idx + 1] = incl;
    cursor[idx] = incl - deg[idx];
    if (idx == 0) rowptr[0] = 0;
  }
}

__global__ void k_scatter(const int* __restrict__ ei, int* __restrict__ cursor,
                          int* __restrict__ esrc) {
  int i = (int)blockIdx.x * blockDim.x + threadIdx.x;
  if (i >= NTOT) return;
  int s, d;
  if (i < NEDGE) { s = ei[i]; d = ei[NEDGE + i]; }
  else           { s = i - NEDGE; d = s; }
  int pos = atomicAdd(cursor + d, 1);
  esrc[pos] = s;
}

// ------- layer-1 aggregate + bias + relu + layer-2 linear/logits -------
// one wave per dst node; half-wave per edge; packed h2c output.
__global__ __launch_bounds__(256) void k_agg1(
    const unsigned short* __restrict__ h1b, const float* __restrict__ als1,
    const float* __restrict__ ald1, const int* __restrict__ rowptr,
    const int* __restrict__ esrc, const float* __restrict__ b1,
    const float* __restrict__ W2, const float* __restrict__ a_s2,
    const float* __restrict__ a_d2, float4* __restrict__ h2c) {
  const int w = threadIdx.x >> 6, lane = threadIdx.x & 63;
  const int d = (int)blockIdx.x * 4 + w;           // grid = 12500
  const int half = lane >> 5, cl = lane & 31;
  const int head = cl >> 3;
  const float ald = ald1[d * 4 + head];
  const int begin = rowptr[d], end = rowptr[d + 1];
  float acc[8];
#pragma unroll
  for (int i = 0; i < 8; ++i) acc[i] = 0.f;
  float S = 0.f;

  int j = begin + half;
  int s = (j < end) ? esrc[j] : -1;
  while (s >= 0) {
    const uint4 hv = *(const uint4*)(h1b + (size_t)s * 256 + cl * 8);
    float e = als1[s * 4 + head] + ald;
    int jn = j + 2;
    int sn = (jn < end) ? esrc[jn] : -1;
    e = fmaxf(e, 0.2f * e);               // leaky relu
    float wgt = __expf(e);
    S += wgt;
    acc[0] += wgt * bflo(hv.x); acc[1] += wgt * bfhi(hv.x);
    acc[2] += wgt * bflo(hv.y); acc[3] += wgt * bfhi(hv.y);
    acc[4] += wgt * bflo(hv.z); acc[5] += wgt * bfhi(hv.z);
    acc[6] += wgt * bflo(hv.w); acc[7] += wgt * bfhi(hv.w);
    j = jn; s = sn;
  }
  // combine the two half-waves
  S += __shfl_xor(S, 32, 64);
#pragma unroll
  for (int i = 0; i < 8; ++i) acc[i] += __shfl_xor(acc[i], 32, 64);

  const float inv = 1.f / S;
  const int c0 = cl * 8;
  float4 ba = *(const float4*)(b1 + c0);
  float4 bb = *(const float4*)(b1 + c0 + 4);
  float bias[8] = {ba.x, ba.y, ba.z, ba.w, bb.x, bb.y, bb.z, bb.w};
  float4 w0 = *(const float4*)(W2 + c0 * 2);
  float4 w1 = *(const float4*)(W2 + c0 * 2 + 4);
  float4 w2 = *(const float4*)(W2 + c0 * 2 + 8);
  float4 w3 = *(const float4*)(W2 + c0 * 2 + 12);
  float wa[16] = {w0.x, w0.y, w0.z, w0.w, w1.x, w1.y, w1.z, w1.w,
                  w2.x, w2.y, w2.z, w2.w, w3.x, w3.y, w3.z, w3.w};
  float p0 = 0.f, p1 = 0.f;
#pragma unroll
  for (int i = 0; i < 8; ++i) {
    float v = acc[i] * inv + bias[i];
    v = v > 0.f ? v : 0.f;
    p0 += v * wa[2 * i];
    p1 += v * wa[2 * i + 1];
  }
#pragma unroll
  for (int m = 1; m < 32; m <<= 1) {
    p0 += __shfl_xor(p0, m, 64);
    p1 += __shfl_xor(p1, m, 64);
  }
  if (lane == 0) {
    h2c[d] = make_float4(p0, p1,
                         p0 * a_s2[0] + p1 * a_s2[1],
                         p0 * a_d2[0] + p1 * a_d2[1]);
  }
}

// ---------------- layer-2 aggregate -> out (thread per dst) ----------------
__global__ __launch_bounds__(256) void k_agg2(
    const float4* __restrict__ h2c, const int* __restrict__ rowptr,
    const int* __restrict__ esrc, const float* __restrict__ b2,
    float* __restrict__ out) {
  int d = (int)blockIdx.x * 256 + threadIdx.x;
  if (d >= NNODE) return;
  const float ald = h2c[d].w;
  const int begin = rowptr[d], end = rowptr[d + 1];
  float S = 0.f, a0 = 0.f, a1 = 0.f;
  for (int j = begin; j < end; ++j) {
    int s = esrc[j];
    float4 v = h2c[s];
    float e = v.z + ald;
    e = fmaxf(e, 0.2f * e);
    float wgt = __expf(e);
    S += wgt;
    a0 += wgt * v.x;
    a1 += wgt * v.y;
  }
  float inv = 1.f / S;
  out[d * 2 + 0] = a0 * inv + b2[0];
  out[d * 2 + 1] = a1 * inv + b2[1];
}

static inline size_t algn(size_t x) { return (x + 255) & ~(size_t)255; }

extern "C" void kernel_launch(void* const* d_in, const int* in_sizes, int n_in,
                              void* d_out, int out_size, void* d_ws, size_t ws_size,
                              hipStream_t stream) {
  const float* x    = (const float*)d_in[0];
  const int*   ei   = (const int*)d_in[1];
  const float* W1   = (const float*)d_in[2];
  const float* a_s1 = (const float*)d_in[3];
  const float* a_d1 = (const float*)d_in[4];
  const float* b1   = (const float*)d_in[5];
  const float* W2   = (const float*)d_in[6];
  const float* a_s2 = (const float*)d_in[7];
  const float* a_d2 = (const float*)d_in[8];
  const float* b2   = (const float*)d_in[9];
  float* out = (float*)d_out;

  char* w = (char*)d_ws;
  size_t o = 0;
  unsigned short* h1b = (unsigned short*)(w + o); o += algn((size_t)NNODE * 256 * 2);
  unsigned short* W1bT = (unsigned short*)(w + o); o += algn((size_t)256 * 128 * 2);
  float* als1 = (float*)(w + o); o += algn((size_t)NNODE * 4 * 4);
  float* ald1 = (float*)(w + o); o += algn((size_t)NNODE * 4 * 4);
  int*   deg  = (int*)(w + o);   o += algn((size_t)NNODE * 4);
  int*   rowp = (int*)(w + o);   o += algn((size_t)(NNODE + 1) * 4);
  int*   curs = (int*)(w + o);   o += algn((size_t)NNODE * 4);
  int*   esrc = (int*)(w + o);   o += algn((size_t)NTOT * 4);
  int*   bsum = (int*)(w + o);   o += 256;
  float4* h2c = (float4*)(w + o); o += algn((size_t)NNODE * 16);
  (void)ws_size; (void)n_in; (void)in_sizes; (void)out_size;

  k_prep<<<dim3(32 + 196), dim3(256), 0, stream>>>(W1, W1bT, deg);
  k_gemm_deg<<<dim3(NGEMM + (NTOT + 255) / 256), dim3(256), 0, stream>>>(
      x, W1bT, a_s1, a_d1, h1b, als1, ald1, ei, deg);
  k_scan1<<<dim3(NB_SCAN), dim3(1024), 0, stream>>>(deg, rowp, bsum);
  k_scan23<<<dim3((NNODE + 255) / 256), dim3(256), 0, stream>>>(deg, rowp, bsum, curs);
  k_scatter<<<dim3((NTOT + 255) / 256), dim3(256), 0, stream>>>(ei, curs, esrc);
  k_agg1<<<dim3(12500), dim3(256), 0, stream>>>(h1b, als1, ald1, rowp, esrc, b1,
                                                W2, a_s2, a_d2, h2c);
  k_agg2<<<dim3((NNODE + 255) / 256), dim3(256), 0, stream>>>(h2c, rowp, esrc, b2, out);
}